// Round 6
// baseline (101.207 us; speedup 1.0000x reference)
//
#include <hip/hip_runtime.h>

// state[e, g, t, c] = sum_{s<=t} param_1 * disp[e, s]
// -> cumsum over t (T=128), broadcast over g (8) and c (6).
// Output [E, 8, 128, 6] fp32: write-bound (491.5 MB writes vs 10.2 MB reads).
// R3: NT float4 stores: 95.4 us, passed.
// R4: 4 elem/block: REGRESSED (100.5) — fewer blocks hurt concurrency. Reverted.
// R5: compute-once val[] + NT: fast but FAILED post-timing revalidation
//     (replay nondeterminism — NT/poison interaction suspected).
// R6: R5 structure with PLAIN stores. The harness's own fills hit 6.9 TB/s
//     with plain stores, so NT is not needed for the write ceiling.

#define T_LEN 128
#define PER_ELEM (8 * T_LEN * 6)       // 6144 floats per element

typedef float f32x4 __attribute__((ext_vector_type(4)));

__global__ __launch_bounds__(256) void state_cumsum_bcast(
    const float* __restrict__ disp,    // [E, 128]
    const float* __restrict__ param1,  // [1]
    float* __restrict__ out,           // [E, 8, 128, 6]
    int n_elem) {
  __shared__ float cum[T_LEN];

  const int e = blockIdx.x;
  if (e >= n_elem) return;
  const int tid  = threadIdx.x;
  const int wv   = tid >> 6;
  const int lane = tid & 63;

  if (tid < 64) {
    const float p = param1[0];
    // two 64-lane segments cover T=128; coalesced 256B loads
    float x0 = p * disp[(size_t)e * T_LEN + lane];
    float x1 = p * disp[(size_t)e * T_LEN + 64 + lane];
    // inclusive scan across 64 lanes (wave = 64 on CDNA)
    #pragma unroll
    for (int d = 1; d < 64; d <<= 1) {
      float y0 = __shfl_up(x0, d, 64);
      float y1 = __shfl_up(x1, d, 64);
      if (lane >= d) { x0 += y0; x1 += y1; }
    }
    const float total0 = __shfl(x0, 63, 64);
    cum[lane]      = x0;
    cum[64 + lane] = x1 + total0;
  }
  __syncthreads();

  // One g-block = 128 t x 6 c = 768 floats = 192 float4 = 3 per lane.
  // f in [0,768): t = f/6 (max 127), value = cum[t] for all c.
  f32x4 val[3];
  #pragma unroll
  for (int i = 0; i < 3; ++i) {
    const int f = 4 * (i * 64 + lane);
    val[i].x = cum[(f + 0) / 6];
    val[i].y = cum[(f + 1) / 6];
    val[i].z = cum[(f + 2) / 6];
    val[i].w = cum[(f + 3) / 6];
  }

  // 8 g-blocks are identical; each wave streams 2 of them (pure addr bump).
  f32x4* o4 = reinterpret_cast<f32x4*>(out + (size_t)e * PER_ELEM);
  #pragma unroll
  for (int r = 0; r < 2; ++r) {
    const int g = wv * 2 + r;
    #pragma unroll
    for (int i = 0; i < 3; ++i) {
      o4[g * 192 + i * 64 + lane] = val[i];
    }
  }
}

extern "C" void kernel_launch(void* const* d_in, const int* in_sizes, int n_in,
                              void* d_out, int out_size, void* d_ws, size_t ws_size,
                              hipStream_t stream) {
  const float* disp   = (const float*)d_in[0];  // [E, 128]
  const float* param1 = (const float*)d_in[1];  // [1]
  float* out = (float*)d_out;

  const int n_elem = in_sizes[0] / T_LEN;       // 20000

  state_cumsum_bcast<<<n_elem, 256, 0, stream>>>(disp, param1, out, n_elem);
}

// Round 7
// 101.148 us; speedup vs baseline: 1.0006x; 1.0006x over previous
//
#include <hip/hip_runtime.h>

// state[e, g, t, c] = sum_{s<=t} param_1 * disp[e, s]
// -> cumsum over t (T=128), broadcast over g (8) and c (6).
// Output [E, 8, 128, 6] fp32: write-bound (491.5 MB writes vs 10.2 MB reads).
// R3: NT float4 stores: 95.4 us (NT later shown determinism-suspect in R5).
// R4: 4 elem/block: 100.5. R6: compute-once + plain stores: 101.2 (~= R1).
//     => per-store VALU overhead irrelevant; plain-store variants pinned ~101.
// R7: persistent zero-barrier kernel. 1024 blocks (16 waves/CU, fully
//     co-resident, no block churn). Each WAVE owns elements grid-stride:
//     private LDS slice (wave-local lgkmcnt ordering, NO __syncthreads),
//     manual prefetch of next element's disp under the store burst.

#define T_LEN 128
#define PER_ELEM (8 * T_LEN * 6)       // 6144 floats per element
#define NBLK 1024
#define WPB  4                          // waves per block (256 threads)
#define NWAVES (NBLK * WPB)             // 4096 waves, grid-stride over elements

typedef float f32x4 __attribute__((ext_vector_type(4)));

__global__ __launch_bounds__(256) void state_cumsum_bcast(
    const float* __restrict__ disp,    // [E, 128]
    const float* __restrict__ param1,  // [1]
    float* __restrict__ out,           // [E, 8, 128, 6]
    int n_elem) {
  __shared__ float cum[WPB][T_LEN];    // per-wave private slice: no barriers

  const int tid  = threadIdx.x;
  const int wv   = tid >> 6;
  const int lane = tid & 63;
  const int wave_id = blockIdx.x * WPB + wv;
  const float p = param1[0];

  int e = wave_id;
  if (e >= n_elem) return;

  // head loads for the first owned element
  float a0 = disp[(size_t)e * T_LEN + lane];
  float a1 = disp[(size_t)e * T_LEN + 64 + lane];

  while (true) {
    const int e_next = e + NWAVES;
    float b0 = 0.f, b1 = 0.f;
    if (e_next < n_elem) {             // prefetch: hides under store burst
      b0 = disp[(size_t)e_next * T_LEN + lane];
      b1 = disp[(size_t)e_next * T_LEN + 64 + lane];
    }

    // inclusive scan across 64 lanes, two segments cover T=128
    float x0 = p * a0, x1 = p * a1;
    #pragma unroll
    for (int d = 1; d < 64; d <<= 1) {
      float y0 = __shfl_up(x0, d, 64);
      float y1 = __shfl_up(x1, d, 64);
      if (lane >= d) { x0 += y0; x1 += y1; }
    }
    const float total0 = __shfl(x0, 63, 64);
    cum[wv][lane]      = x0;
    cum[wv][64 + lane] = x1 + total0;  // wave-local LDS: lgkmcnt orders it

    // One g-block = 768 floats = 192 float4 = 3 per lane; t = f/6 (<128).
    f32x4 val[3];
    #pragma unroll
    for (int i = 0; i < 3; ++i) {
      const int f = 4 * (i * 64 + lane);
      val[i].x = cum[wv][(f + 0) / 6];
      val[i].y = cum[wv][(f + 1) / 6];
      val[i].z = cum[wv][(f + 2) / 6];
      val[i].w = cum[wv][(f + 3) / 6];
    }

    // 8 identical g-blocks: 24 x 1KB contiguous coalesced stores.
    f32x4* o4 = reinterpret_cast<f32x4*>(out + (size_t)e * PER_ELEM);
    #pragma unroll
    for (int g = 0; g < 8; ++g) {
      #pragma unroll
      for (int i = 0; i < 3; ++i) {
        o4[g * 192 + i * 64 + lane] = val[i];
      }
    }

    if (e_next >= n_elem) break;
    e = e_next; a0 = b0; a1 = b1;
  }
}

extern "C" void kernel_launch(void* const* d_in, const int* in_sizes, int n_in,
                              void* d_out, int out_size, void* d_ws, size_t ws_size,
                              hipStream_t stream) {
  const float* disp   = (const float*)d_in[0];  // [E, 128]
  const float* param1 = (const float*)d_in[1];  // [1]
  float* out = (float*)d_out;

  const int n_elem = in_sizes[0] / T_LEN;       // 20000

  state_cumsum_bcast<<<NBLK, 256, 0, stream>>>(disp, param1, out, n_elem);
}

// Round 8
// 97.215 us; speedup vs baseline: 1.0411x; 1.0405x over previous
//
#include <hip/hip_runtime.h>

// state[e, g, t, c] = sum_{s<=t} param_1 * disp[e, s]
// -> cumsum over t (T=128), broadcast over g (8) and c (6).
// Output [E, 8, 128, 6] fp32: write-bound (491.5 MB writes vs 10.2 MB reads).
// R3: NT stores 95.4 us (NT determinism-suspect per R5's post-timing fail).
// R4/R6/R7: 4elem-block / compute-once / persistent+prefetch all ~101 us
//     => plain-store variants pinned at 4.86 TB/s regardless of structure.
// R8: theory = HBM read<->write turnaround from the fine-grained interleaved
//     read stream. Fix: phase-separate. Each wave loads ALL its (<=5)
//     elements' disp upfront (read phase ~2 us grid-wide), then the rest of
//     the dispatch is a PURE write stream like the 6.9 TB/s fills.

#define T_LEN 128
#define PER_ELEM (8 * T_LEN * 6)       // 6144 floats per element
#define NBLK 1024
#define WPB  4                          // waves per block (256 threads)
#define NWAVES (NBLK * WPB)             // 4096 waves, grid-stride over elements
#define MAX_ITERS 5                     // ceil(20000 / 4096)

typedef float f32x4 __attribute__((ext_vector_type(4)));

__global__ __launch_bounds__(256) void state_cumsum_bcast(
    const float* __restrict__ disp,    // [E, 128]
    const float* __restrict__ param1,  // [1]
    float* __restrict__ out,           // [E, 8, 128, 6]
    int n_elem) {
  __shared__ float cum[WPB][T_LEN];    // per-wave private slice: no barriers

  const int tid  = threadIdx.x;
  const int wv   = tid >> 6;
  const int lane = tid & 63;
  const int wave_id = blockIdx.x * WPB + wv;
  const float p = param1[0];

  // ---- READ PHASE: issue every owned element's loads back-to-back ----
  float a0[MAX_ITERS], a1[MAX_ITERS];
  #pragma unroll
  for (int k = 0; k < MAX_ITERS; ++k) {
    const int e = wave_id + k * NWAVES;
    if (e < n_elem) {
      a0[k] = disp[(size_t)e * T_LEN + lane];        // coalesced 256B
      a1[k] = disp[(size_t)e * T_LEN + 64 + lane];
    } else {
      a0[k] = 0.f; a1[k] = 0.f;
    }
  }
  __builtin_amdgcn_sched_barrier(0);   // pin: all reads issue before write phase

  // ---- WRITE PHASE: scan + broadcast, zero further global reads ----
  #pragma unroll
  for (int k = 0; k < MAX_ITERS; ++k) {
    const int e = wave_id + k * NWAVES;
    if (e >= n_elem) break;

    // inclusive scan across 64 lanes, two segments cover T=128
    float x0 = p * a0[k], x1 = p * a1[k];
    #pragma unroll
    for (int d = 1; d < 64; d <<= 1) {
      float y0 = __shfl_up(x0, d, 64);
      float y1 = __shfl_up(x1, d, 64);
      if (lane >= d) { x0 += y0; x1 += y1; }
    }
    const float total0 = __shfl(x0, 63, 64);
    cum[wv][lane]      = x0;
    cum[wv][64 + lane] = x1 + total0;  // wave-local LDS: lgkmcnt orders it

    // One g-block = 768 floats = 192 float4 = 3 per lane; t = f/6 (<128).
    f32x4 val[3];
    #pragma unroll
    for (int i = 0; i < 3; ++i) {
      const int f = 4 * (i * 64 + lane);
      val[i].x = cum[wv][(f + 0) / 6];
      val[i].y = cum[wv][(f + 1) / 6];
      val[i].z = cum[wv][(f + 2) / 6];
      val[i].w = cum[wv][(f + 3) / 6];
    }

    // 8 identical g-blocks: 24 x 1KB contiguous coalesced stores.
    f32x4* o4 = reinterpret_cast<f32x4*>(out + (size_t)e * PER_ELEM);
    #pragma unroll
    for (int g = 0; g < 8; ++g) {
      #pragma unroll
      for (int i = 0; i < 3; ++i) {
        o4[g * 192 + i * 64 + lane] = val[i];
      }
    }
  }
}

extern "C" void kernel_launch(void* const* d_in, const int* in_sizes, int n_in,
                              void* d_out, int out_size, void* d_ws, size_t ws_size,
                              hipStream_t stream) {
  const float* disp   = (const float*)d_in[0];  // [E, 128]
  const float* param1 = (const float*)d_in[1];  // [1]
  float* out = (float*)d_out;

  const int n_elem = in_sizes[0] / T_LEN;       // 20000

  state_cumsum_bcast<<<NBLK, 256, 0, stream>>>(disp, param1, out, n_elem);
}

// Round 9
// 97.153 us; speedup vs baseline: 1.0417x; 1.0006x over previous
//
#include <hip/hip_runtime.h>

// state[e, g, t, c] = sum_{s<=t} param_1 * disp[e, s]
// -> cumsum over t (T=128), broadcast over g (8) and c (6).
// Output [E, 8, 128, 6] fp32: write-bound (491.5 MB writes vs 10.2 MB reads).
// R3: NT stores 95.4 us (NT determinism-suspect per R5 post-timing fail).
// R4/R6/R7: structural variants all ~101 us (plain stores ~4.9 TB/s).
// R8: phase-separated reads (all disp loads upfront) 97.2 us (+4%).
// R9: perfect load balance: 1250 blocks x 4 waves = 5000 waves, EXACTLY
//     4 elements each (20000 = 5000*4). No straggler waves, no block churn
//     (4.9 blocks/CU all-resident), hot path free of bounds checks.

#define T_LEN 128
#define PER_ELEM (8 * T_LEN * 6)       // 6144 floats per element
#define NBLK 1250
#define WPB  4                          // waves per block (256 threads)
#define NWAVES (NBLK * WPB)             // 5000 waves
#define ITERS 4                         // 20000 / 5000 exactly

typedef float f32x4 __attribute__((ext_vector_type(4)));

__global__ __launch_bounds__(256) void state_cumsum_bcast(
    const float* __restrict__ disp,    // [E, 128]
    const float* __restrict__ param1,  // [1]
    float* __restrict__ out,           // [E, 8, 128, 6]
    int n_elem) {
  __shared__ float cum[WPB][T_LEN];    // per-wave private slice: no barriers

  const int tid  = threadIdx.x;
  const int wv   = tid >> 6;
  const int lane = tid & 63;
  const int wave_id = blockIdx.x * WPB + wv;
  const float p = param1[0];

  // ---- READ PHASE: all owned elements' disp loads issued back-to-back ----
  float a0[ITERS], a1[ITERS];
  #pragma unroll
  for (int k = 0; k < ITERS; ++k) {
    const int e = wave_id + k * NWAVES;
    if (e < n_elem) {                  // always true at E=20000; keeps generality
      a0[k] = disp[(size_t)e * T_LEN + lane];        // coalesced 256B
      a1[k] = disp[(size_t)e * T_LEN + 64 + lane];
    } else {
      a0[k] = 0.f; a1[k] = 0.f;
    }
  }
  __builtin_amdgcn_sched_barrier(0);   // all reads issue before write phase

  // ---- WRITE PHASE: scan + broadcast, zero further global reads ----
  #pragma unroll
  for (int k = 0; k < ITERS; ++k) {
    const int e = wave_id + k * NWAVES;
    if (e >= n_elem) break;

    // inclusive scan across 64 lanes, two segments cover T=128
    float x0 = p * a0[k], x1 = p * a1[k];
    #pragma unroll
    for (int d = 1; d < 64; d <<= 1) {
      float y0 = __shfl_up(x0, d, 64);
      float y1 = __shfl_up(x1, d, 64);
      if (lane >= d) { x0 += y0; x1 += y1; }
    }
    const float total0 = __shfl(x0, 63, 64);
    cum[wv][lane]      = x0;
    cum[wv][64 + lane] = x1 + total0;  // wave-local LDS: lgkmcnt orders it

    // One g-block = 768 floats = 192 float4 = 3 per lane; t = f/6 (<128).
    f32x4 val[3];
    #pragma unroll
    for (int i = 0; i < 3; ++i) {
      const int f = 4 * (i * 64 + lane);
      val[i].x = cum[wv][(f + 0) / 6];
      val[i].y = cum[wv][(f + 1) / 6];
      val[i].z = cum[wv][(f + 2) / 6];
      val[i].w = cum[wv][(f + 3) / 6];
    }

    // 8 identical g-blocks: 24 x 1KB contiguous coalesced stores.
    f32x4* o4 = reinterpret_cast<f32x4*>(out + (size_t)e * PER_ELEM);
    #pragma unroll
    for (int g = 0; g < 8; ++g) {
      #pragma unroll
      for (int i = 0; i < 3; ++i) {
        o4[g * 192 + i * 64 + lane] = val[i];
      }
    }
  }
}

extern "C" void kernel_launch(void* const* d_in, const int* in_sizes, int n_in,
                              void* d_out, int out_size, void* d_ws, size_t ws_size,
                              hipStream_t stream) {
  const float* disp   = (const float*)d_in[0];  // [E, 128]
  const float* param1 = (const float*)d_in[1];  // [1]
  float* out = (float*)d_out;

  const int n_elem = in_sizes[0] / T_LEN;       // 20000

  state_cumsum_bcast<<<NBLK, 256, 0, stream>>>(disp, param1, out, n_elem);
}